// Round 4
// baseline (235.733 us; speedup 1.0000x reference)
//
#include <hip/hip_runtime.h>

// Problem constants (from reference setup_inputs)
constexpr int B = 4, C = 96, H = 192, W = 320;
constexpr int HW      = H * W;       // 61440 floats per (b,c) plane
constexpr int HW4     = HW / 4;      // 15360 float4 per (b,c) plane
constexpr int OUT_CH  = 81;
constexpr int TOTAL_S4   = B * HW4;           // 61440 corr float4s
constexpr int TOTAL_OUT4 = B * OUT_CH * HW4;  // 4,976,640 output float4s

// Phase-1 tiling: 16 KB contiguous runs per (block, channel) to fix DRAM
// row thrash (R3: 1 KB runs at 240 KB stride -> 1.3 TB/s HBM reads).
constexpr int TILE4   = 1024;        // spatial float4 per block (16 KB run)
constexpr int NTILES  = TOTAL_S4 / TILE4;   // 60 (divides exactly; 15 per b)
constexpr int TPP     = HW4 / TILE4;        // 15 tiles per (b) plane
constexpr int SPLITC  = 8;           // channel split
constexpr int CPGRP   = C / SPLITC;  // 12 channels per group
constexpr int ELEMS_PT = TILE4 / 256;       // 4 float4 per thread

typedef float f32x4 __attribute__((ext_vector_type(4)));

// ws layout: [ pd: SPLITC*TOTAL_S4 f4 ][ pa: SPLITC*TOTAL_S4 f4 ][ corr: TOTAL_S4 f4 ]
constexpr size_t PD_F4   = (size_t)SPLITC * TOTAL_S4;       // 491,520 f4
constexpr size_t WS_F4   = 2 * PD_F4 + TOTAL_S4;            // + corr
constexpr size_t WS_NEED = WS_F4 * sizeof(f32x4);           // ~16.7 MB

// ---------------- Phase 1: partial dot/asum, linear 16 KB runs ----------------
// Block = (tile t, channel-group g). Thread k reads positions
// tileoff + tid + {0,256,512,768}: the block streams 16 KB of f1 and 16 KB of
// f2 contiguously per channel. 480 blocks, all co-resident.
__global__ __launch_bounds__(256) void corr_partial(
    const f32x4* __restrict__ f1,
    const f32x4* __restrict__ f2,
    f32x4* __restrict__ pd,
    f32x4* __restrict__ pa)
{
    const int t = blockIdx.x % NTILES;       // spatial tile
    const int g = blockIdx.x / NTILES;       // channel group
    const int b = t / TPP;
    const int tileoff = (t - b * TPP) * TILE4;   // f4 offset within plane
    const int p0 = tileoff + threadIdx.x;        // first of 4 positions

    const f32x4* __restrict__ q1 = f1 + ((size_t)(b * C + g * CPGRP)) * HW4 + p0;
    const f32x4* __restrict__ q2 = f2 + ((size_t)(b * C + g * CPGRP)) * HW4 + p0;

    f32x4 d[ELEMS_PT], a[ELEMS_PT];
#pragma unroll
    for (int k = 0; k < ELEMS_PT; ++k) {
        d[k] = (f32x4){0.f, 0.f, 0.f, 0.f};
        a[k] = (f32x4){0.f, 0.f, 0.f, 0.f};
    }

#pragma unroll 2
    for (int j = 0; j < CPGRP; ++j) {
        f32x4 x[ELEMS_PT], y[ELEMS_PT];
#pragma unroll
        for (int k = 0; k < ELEMS_PT; ++k)
            x[k] = q1[(size_t)j * HW4 + k * 256];
#pragma unroll
        for (int k = 0; k < ELEMS_PT; ++k)
            y[k] = q2[(size_t)j * HW4 + k * 256];
#pragma unroll
        for (int k = 0; k < ELEMS_PT; ++k) {
            d[k].x = fmaf(x[k].x, y[k].x, d[k].x);
            d[k].y = fmaf(x[k].y, y[k].y, d[k].y);
            d[k].z = fmaf(x[k].z, y[k].z, d[k].z);
            d[k].w = fmaf(x[k].w, y[k].w, d[k].w);
            a[k].x += fabsf(x[k].x);
            a[k].y += fabsf(x[k].y);
            a[k].z += fabsf(x[k].z);
            a[k].w += fabsf(x[k].w);
        }
    }

    // partials: [g][b*HW4 + spatial]
    const size_t base = (size_t)g * TOTAL_S4 + (size_t)b * HW4 + p0;
#pragma unroll
    for (int k = 0; k < ELEMS_PT; ++k) {
        __builtin_nontemporal_store(d[k], pd + base + k * 256);
        __builtin_nontemporal_store(a[k], pa + base + k * 256);
    }
}

// ---------------- Phase 1b: reduce 8 partials -> corr map ----------------
__global__ __launch_bounds__(256) void corr_reduce(
    const f32x4* __restrict__ pd,
    const f32x4* __restrict__ pa,
    f32x4* __restrict__ corr)
{
    const int idx = blockIdx.x * 256 + threadIdx.x;   // [0, TOTAL_S4)
    f32x4 dt = {0.f, 0.f, 0.f, 0.f};
    f32x4 at = {0.f, 0.f, 0.f, 0.f};
#pragma unroll
    for (int g = 0; g < SPLITC; ++g) {
        const f32x4 dk = pd[(size_t)g * TOTAL_S4 + idx];
        const f32x4 ak = pa[(size_t)g * TOTAL_S4 + idx];
        dt.x += dk.x; dt.y += dk.y; dt.z += dk.z; dt.w += dk.w;
        at.x += ak.x; at.y += ak.y; at.z += ak.z; at.w += ak.w;
    }
    const float inv_c = 1.0f / (float)C;
    f32x4 r;
    r.x = (at.x > 0.1f) ? dt.x * inv_c : 0.0f;
    r.y = (at.y > 0.1f) ? dt.y * inv_c : 0.0f;
    r.z = (at.z > 0.1f) ? dt.z * inv_c : 0.0f;
    r.w = (at.w > 0.1f) ? dt.w * inv_c : 0.0f;
    corr[idx] = r;   // stays cached for phase 2
}

// ---------------- Phase 2: broadcast (writes-only, linear NT stores) ----------
__global__ __launch_bounds__(256) void corr_phase2(
    const f32x4* __restrict__ corr,
    f32x4* __restrict__ out)
{
    const int idx   = blockIdx.x * 256 + threadIdx.x;   // [0, TOTAL_OUT4)
    const int plane = idx / HW4;                        // = b*81 + o
    const int s4    = idx - plane * HW4;
    const int b     = plane / OUT_CH;
    const f32x4 r = corr[(size_t)b * HW4 + s4];
    __builtin_nontemporal_store(r, out + idx);
}

// ---------------- Fallback (ws too small): R2 single kernel ----------------
__global__ __launch_bounds__(256) void spike_corr_mono(
    const float* __restrict__ f1,
    const float* __restrict__ f2,
    float* __restrict__ out)
{
    const int idx = blockIdx.x * blockDim.x + threadIdx.x;
    const int b = idx / HW;
    const int s = idx - b * HW;
    const float* __restrict__ p1 = f1 + (size_t)b * C * HW + s;
    const float* __restrict__ p2 = f2 + (size_t)b * C * HW + s;
    float dot = 0.f, asum = 0.f;
#pragma unroll 16
    for (int c = 0; c < C; ++c) {
        const float av = p1[(size_t)c * HW];
        const float vv = p2[(size_t)c * HW];
        dot = fmaf(av, vv, dot);
        asum += fabsf(av);
    }
    const float r = (asum > 0.1f) ? dot * (1.0f / (float)C) : 0.0f;
    float* __restrict__ po = out + (size_t)b * OUT_CH * HW + s;
#pragma unroll 1
    for (int o = 0; o < OUT_CH; ++o)
        __builtin_nontemporal_store(r, po + (size_t)o * HW);
}

extern "C" void kernel_launch(void* const* d_in, const int* in_sizes, int n_in,
                              void* d_out, int out_size, void* d_ws, size_t ws_size,
                              hipStream_t stream) {
    if (ws_size >= WS_NEED) {
        const f32x4* f1 = (const f32x4*)d_in[0];
        const f32x4* f2 = (const f32x4*)d_in[1];
        f32x4* pd   = (f32x4*)d_ws;
        f32x4* pa   = pd + PD_F4;
        f32x4* corr = pa + PD_F4;
        f32x4* out  = (f32x4*)d_out;

        corr_partial<<<NTILES * SPLITC, 256, 0, stream>>>(f1, f2, pd, pa); // 480 blocks
        corr_reduce<<<TOTAL_S4 / 256, 256, 0, stream>>>(pd, pa, corr);     // 240 blocks
        corr_phase2<<<TOTAL_OUT4 / 256, 256, 0, stream>>>(corr, out);      // 19440 blocks
    } else {
        const float* f1 = (const float*)d_in[0];
        const float* f2 = (const float*)d_in[1];
        float* out = (float*)d_out;
        spike_corr_mono<<<(B * HW) / 256, 256, 0, stream>>>(f1, f2, out);
    }
}